// Round 1
// baseline (473.014 us; speedup 1.0000x reference)
//
#include <hip/hip_runtime.h>
#include <hip/hip_bf16.h>

#define N_   4
#define CIN  1024
#define H_   56
#define W_   56
#define HW   3136
#define CB   256
#define KK   9
#define OFFC 18

typedef __attribute__((ext_vector_type(8))) short short8;
typedef __attribute__((ext_vector_type(4))) short short4v;
typedef __attribute__((ext_vector_type(4))) float float4v;
typedef unsigned short ushort_t;

// fp32 -> bf16 round-to-nearest-even
__device__ inline ushort_t bf16_rne(float f) {
    unsigned int u = __float_as_uint(f);
    unsigned int r = (u + 0x7FFFu + ((u >> 16) & 1u)) >> 16;
    return (ushort_t)r;
}
__device__ inline void split_bf16(float f, ushort_t& hi, ushort_t& lo) {
    ushort_t h = bf16_rne(f);
    float hf = __uint_as_float(((unsigned int)h) << 16);
    hi = h;
    lo = bf16_rne(f - hf);
}
__device__ inline short8 ld_frag_lds(const ushort_t* base) {
    short4v a = *(const short4v*)base;
    short4v b = *(const short4v*)(base + 4);
    return __builtin_shufflevector(a, b, 0, 1, 2, 3, 4, 5, 6, 7);
}

// ---------------------------------------------------------------------------
// Pack weights.
// w1 [256][1024]      -> w1p [o][2][1024]   (hi/lo)
// w2 [256][256][9]    -> w2p [k][o][256]    (hi only)
// w3 [1024][256]      -> w3p [o][2][256]    (hi/lo)
// w_off [18][256][9]  -> wofp [k][32][256]  (hi only, m padded 18->32)
// ---------------------------------------------------------------------------
__global__ void __launch_bounds__(256) pack_weights_kernel(
    const float* __restrict__ w1, const float* __restrict__ w2,
    const float* __restrict__ w3, const float* __restrict__ w_off,
    ushort_t* __restrict__ w1p, ushort_t* __restrict__ w2p,
    ushort_t* __restrict__ w3p, ushort_t* __restrict__ wofp)
{
    int e = blockIdx.x * 256 + threadIdx.x;
    if (e < 256 * 1024) {
        int o = e >> 10, k = e & 1023;
        ushort_t hi, lo; split_bf16(w1[e], hi, lo);
        w1p[(size_t)(o * 2 + 0) * 1024 + k] = hi;
        w1p[(size_t)(o * 2 + 1) * 1024 + k] = lo;
        return;
    }
    e -= 256 * 1024;
    if (e < 256 * 256 * 9) {
        int o = e / 2304; int rem = e % 2304; int c = rem / 9; int k = rem % 9;
        w2p[(size_t)(k * 256 + o) * 256 + c] = bf16_rne(w2[e]);
        return;
    }
    e -= 256 * 256 * 9;
    if (e < 1024 * 256) {
        int o = e >> 8, k = e & 255;
        ushort_t hi, lo; split_bf16(w3[e], hi, lo);
        w3p[(size_t)(o * 2 + 0) * 256 + k] = hi;
        w3p[(size_t)(o * 2 + 1) * 256 + k] = lo;
        return;
    }
    e -= 1024 * 256;
    if (e < 9 * 32 * 256) {
        int k = e / (32 * 256);
        int rem = e % (32 * 256);
        int m = rem >> 8, c = rem & 255;
        float v = (m < OFFC) ? w_off[((size_t)m * 256 + c) * 9 + k] : 0.f;
        wofp[e] = bf16_rne(v);
    }
}

// ---------------------------------------------------------------------------
// 1x1 conv via MFMA. A = weights (hi/lo, 2 passes), B = activations (bf16).
// PSUM: B = relu(Xin + Xin2 + prebias[channel]) — fuses the deform partial-sum
// reduction + bias + relu into the B-load.
// ---------------------------------------------------------------------------
template <int MFRAG, bool RELU, bool RESID, bool PSUM>
__global__ void __launch_bounds__(256, 4) conv1x1_mfma_kernel(
    const ushort_t* __restrict__ Wp,   // [M][2][Kdim]
    const float* __restrict__ Xin,     // [n][Kdim][HW]
    const float* __restrict__ Xin2,    // [n][Kdim][HW] or null
    const float* __restrict__ prebias, // [Kdim] or null
    const float* __restrict__ bias,    // [M]
    const float* __restrict__ resid,   // [n][M][HW] or null
    float* __restrict__ Cout,          // [n][M][HW]
    int M, int Kdim)
{
    __shared__ ushort_t Bs[64][36];   // [p][k], pad 36

    const int tid  = threadIdx.x;
    const int wave = tid >> 6;
    const int lane = tid & 63;
    const int l15  = lane & 15;
    const int quad = lane >> 4;
    const int pBase = blockIdx.x * 64;
    const int mBase = blockIdx.y * (MFRAG * 64) + wave * (MFRAG * 16);
    const int n     = blockIdx.z;
    const float* Xn  = Xin + (size_t)n * Kdim * HW;
    const float* Xn2 = PSUM ? (Xin2 + (size_t)n * Kdim * HW) : nullptr;

    float4v acc[MFRAG][4];
#pragma unroll
    for (int i = 0; i < MFRAG; ++i)
#pragma unroll
        for (int j = 0; j < 4; ++j) acc[i][j] = (float4v)(0.f);

    const int kk = tid >> 3;          // 0..31
    const int pq = (tid & 7) * 8;     // 0..56

    for (int k0 = 0; k0 < Kdim; k0 += 32) {
        const float* src = &Xn[(size_t)(k0 + kk) * HW + pBase + pq];
        float4 v0 = *reinterpret_cast<const float4*>(src);
        float4 v1 = *reinterpret_cast<const float4*>(src + 4);
        float vs[8] = {v0.x, v0.y, v0.z, v0.w, v1.x, v1.y, v1.z, v1.w};
        if (PSUM) {
            const float* src2 = &Xn2[(size_t)(k0 + kk) * HW + pBase + pq];
            float4 u0 = *reinterpret_cast<const float4*>(src2);
            float4 u1 = *reinterpret_cast<const float4*>(src2 + 4);
            float us[8] = {u0.x, u0.y, u0.z, u0.w, u1.x, u1.y, u1.z, u1.w};
            float pb = prebias[k0 + kk];
#pragma unroll
            for (int j = 0; j < 8; ++j) vs[j] = fmaxf(vs[j] + us[j] + pb, 0.f);
        }
        __syncthreads();   // previous iter's Bs reads are done
#pragma unroll
        for (int j = 0; j < 8; ++j) Bs[pq + j][kk] = bf16_rne(vs[j]);
        __syncthreads();

        short8 ah[MFRAG], al[MFRAG];
#pragma unroll
        for (int mt = 0; mt < MFRAG; ++mt) {
            const ushort_t* arow = Wp +
                ((size_t)(mBase + mt * 16 + l15) * 2) * Kdim + k0 + quad * 8;
            ah[mt] = *(const short8*)(arow);
            al[mt] = *(const short8*)(arow + Kdim);
        }
        short8 bh[4];
#pragma unroll
        for (int nt = 0; nt < 4; ++nt)
            bh[nt] = ld_frag_lds(&Bs[nt * 16 + l15][quad * 8]);
#pragma unroll
        for (int mt = 0; mt < MFRAG; ++mt)
#pragma unroll
            for (int nt = 0; nt < 4; ++nt) {
                acc[mt][nt] = __builtin_amdgcn_mfma_f32_16x16x32_bf16(
                    ah[mt], bh[nt], acc[mt][nt], 0, 0, 0);
                acc[mt][nt] = __builtin_amdgcn_mfma_f32_16x16x32_bf16(
                    al[mt], bh[nt], acc[mt][nt], 0, 0, 0);
            }
    }

#pragma unroll
    for (int mt = 0; mt < MFRAG; ++mt)
#pragma unroll
        for (int rr = 0; rr < 4; ++rr) {
            int row = mBase + mt * 16 + quad * 4 + rr;
            float bv = bias[row];
#pragma unroll
            for (int nt = 0; nt < 4; ++nt) {
                int col = pBase + nt * 16 + l15;
                size_t idx = ((size_t)n * M + row) * HW + col;
                float v = acc[mt][nt][rr] + bv;
                if (RESID) v += resid[idx];
                if (RELU)  v = fmaxf(v, 0.f);
                Cout[idx] = v;
            }
        }
}

// ---------------------------------------------------------------------------
// Offset conv 3x3 via MFMA (bf16 1-pass), LDS row-window staging.
// ---------------------------------------------------------------------------
__global__ void __launch_bounds__(256, 2) offset_mfma_kernel(
    const float* __restrict__ r,        // [n][CB][HW]
    const ushort_t* __restrict__ wofp,  // [9][32][256] bf16
    const float* __restrict__ b_off,    // [18]
    float* __restrict__ off)            // [n][18][HW]
{
    __shared__ float win[32][174];      // 3 rows x 56 cols, padded stride

    const int tid  = threadIdx.x;
    const int h    = blockIdx.x;
    const int n    = blockIdx.y;
    const int wave = tid >> 6;
    const int lane = tid & 63;
    const int l15  = lane & 15;
    const int quad = lane >> 4;
    const float* rn = r + (size_t)n * CB * HW;

    const int p = wave * 16 + l15;      // output column this lane covers

    float4v acc[2];
    acc[0] = (float4v)(0.f);
    acc[1] = (float4v)(0.f);

    for (int cb = 0; cb < CB; cb += 32) {
        __syncthreads();
        for (int f = tid; f < 32 * 3 * 14; f += 256) {
            int c = f / 42, remf = f % 42, row = remf / 14, x4 = (remf % 14) * 4;
            int yg = h - 1 + row;
            float4 v = {0.f, 0.f, 0.f, 0.f};
            if (yg >= 0 && yg < H_)
                v = *reinterpret_cast<const float4*>(
                    &rn[(size_t)(cb + c) * HW + yg * W_ + x4]);
            *reinterpret_cast<float4*>(&win[c][row * 56 + x4]) = v;
        }
        __syncthreads();

#pragma unroll
        for (int k = 0; k < KK; ++k) {
            const int ky = k / 3;
            const int dx = (k % 3) - 1;
            int x = p + dx;
            bool pvalid = (p < 56) && (x >= 0) && (x < 56);
            int xc = min(max(x, 0), 55);
            short8 bh;
#pragma unroll
            for (int j = 0; j < 8; ++j) {
                float v = win[quad * 8 + j][ky * 56 + xc];
                bh[j] = (short)bf16_rne(pvalid ? v : 0.f);
            }
#pragma unroll
            for (int mt = 0; mt < 2; ++mt) {
                const ushort_t* arow = wofp +
                    (size_t)(k * 32 + mt * 16 + l15) * 256 + cb + quad * 8;
                short8 ah = *(const short8*)arow;
                acc[mt] = __builtin_amdgcn_mfma_f32_16x16x32_bf16(
                    ah, bh, acc[mt], 0, 0, 0);
            }
        }
    }

    if (p < 56) {
#pragma unroll
        for (int mt = 0; mt < 2; ++mt)
#pragma unroll
            for (int rr = 0; rr < 4; ++rr) {
                int m = mt * 16 + quad * 4 + rr;
                if (m < OFFC)
                    off[((size_t)n * OFFC + m) * HW + h * W_ + p] =
                        acc[mt][rr] + b_off[m];
            }
    }
}

// ---------------------------------------------------------------------------
// Deformable conv via MFMA — v2: latency/occupancy restructure.
// 256 thr = 4 waves; each wave owns 64 output channels (4 m-tiles x 16).
// N-tile 16 (14 real positions = x-quarter of one row).
// K-split: each block reduces 128 of 256 input channels (cbh half) and
// writes fp32 PARTIAL sums to r2h[cbh]; the following 1x1 conv sums the
// two halves and applies bias+relu at load (PSUM path).
// Grid: 1792 one-dim blocks (56 h x 4 xquad x 4 n x 2 cbh), bijective
// XCD swizzle (1792 % 8 == 0), decode n-slowest so each XCD's L2 reuses
// r window rows across x-quads and adjacent h.
// LDS ~29.4 KB -> 5 blocks/CU co-residable (vs 51.2 KB / 2 before).
// Per-block serial chain: 4 chunks x 3 barriers (vs 8 x 3 before).
// ---------------------------------------------------------------------------
#define TPX   14
#define WROWS 5
#define WCOLS 24
#define WPOS  (WROWS * WCOLS)   // 120
#define CSTR  33
#define NBLK  (H_ * 4 * N_ * 2) // 1792

__global__ void __launch_bounds__(256, 4) deform_mfma_kernel(
    const float* __restrict__ r,      // [n][CB][HW]
    const float* __restrict__ off,    // [n][18][HW]
    const ushort_t* __restrict__ w2p, // [9][256][256] bf16 hi
    float* __restrict__ r2h)          // [2][n][CB][HW] fp32 partials
{
    __shared__ float win[WPOS][CSTR];                    // 15840 B
    __shared__ __align__(16) ushort_t Bs[KK][16][36];    // 10368 B
    __shared__ __align__(16) short    widx[KK][TPX][4];  //  1008 B
    __shared__ __align__(16) float    wwgt[KK][TPX][4];  //  2016 B
    __shared__ unsigned char fastf[KK][TPX];             //   126 B

    const int tid = threadIdx.x;
    const int bid = blockIdx.x;
    const int swz = (bid & 7) * (NBLK >> 3) + (bid >> 3);  // bijective, 1792%8==0
    const int cbh = swz & 1;
    const int xq  = (swz >> 1) & 3;
    const int h   = (swz >> 3) % H_;
    const int n   = swz / (H_ * 8);
    const int xb  = xq * TPX;
    const int cb0 = cbh * 128;

    const float* rn   = r + (size_t)n * CB * HW;
    const float* offn = off + (size_t)n * OFFC * HW;

    // ---- per-(tap, position) bilinear metadata, window-relative ----
    if (tid < KK * TPX) {
        int k = tid / TPX, p = tid % TPX;
        int pg = xb + p;
        float dy = offn[(size_t)(2 * k) * HW + h * W_ + pg];
        float dx = offn[(size_t)(2 * k + 1) * HW + h * W_ + pg];
        float ys = (float)(h + (k / 3) - 1) + dy;
        float xs = (float)(pg + (k % 3) - 1) + dx;
        float y0f = floorf(ys), x0f = floorf(xs);
        int y0 = (int)y0f, x0 = (int)x0f;
        float wy1 = ys - y0f, wy0 = 1.f - wy1;
        float wx1 = xs - x0f, wx0 = 1.f - wx1;
        bool fast = true;
#pragma unroll
        for (int u = 0; u < 2; ++u)
#pragma unroll
            for (int vv = 0; vv < 2; ++vv) {
                int yy = y0 + u, xx = x0 + vv;
                bool valid = (yy >= 0) && (yy <= 55) && (xx >= 0) && (xx <= 55);
                float wgt = valid ? (u ? wy1 : wy0) * (vv ? wx1 : wx0) : 0.f;
                int ry = yy - (h - 2);
                int rx = xx - (xb - 4);
                if (wgt != 0.f &&
                    (ry < 0 || ry >= WROWS || rx < 0 || rx >= WCOLS))
                    fast = false;
                int ryc = min(max(ry, 0), WROWS - 1);
                int rxc = min(max(rx, 0), WCOLS - 1);
                widx[k][p][u * 2 + vv] = (short)(ryc * WCOLS + rxc);
                wwgt[k][p][u * 2 + vv] = wgt;
            }
        fastf[k][p] = fast ? 1 : 0;
    }

    const int wave = tid >> 6;     // 0..3
    const int lane = tid & 63;
    const int l15  = lane & 15;
    const int quad = lane >> 4;
    const int mW   = wave * 64;    // wave owns 64 output channels

    float4v acc[4];
#pragma unroll
    for (int i = 0; i < 4; ++i) acc[i] = (float4v)(0.f);

    for (int cb = 0; cb < 128; cb += 32) {
        const int cbg = cb0 + cb;
        __syncthreads();  // prev MFMA Bs/win reads done; metadata visible (1st)
        // ---- stage window: 32 ch x 5 rows x 24 cols (x in [xb-4, xb+20)) ----
        for (int f = tid; f < 32 * WROWS * 6; f += 256) {
            int c = f / 30, remf = f % 30, row = remf / 6, q = remf % 6;
            int yg = min(max(h - 2 + row, 0), H_ - 1);
            int xg = xb - 4 + q * 4;
            const float* src = &rn[(size_t)(cbg + c) * HW + yg * W_];
            float vx[4];
            if (xg >= 0 && xg <= W_ - 4) {
                float4 v = *reinterpret_cast<const float4*>(src + xg);
                vx[0] = v.x; vx[1] = v.y; vx[2] = v.z; vx[3] = v.w;
            } else {
#pragma unroll
                for (int j = 0; j < 4; ++j)
                    vx[j] = src[min(max(xg + j, 0), W_ - 1)];
            }
            int pos = row * WCOLS + q * 4;
#pragma unroll
            for (int j = 0; j < 4; ++j) win[pos + j][c] = vx[j];
        }
        __syncthreads();

        // ---- build B tiles for ALL 9 taps: 9 x 16 p x 32 ch = 4608 ----
#pragma unroll
        for (int ii = 0; ii < 18; ++ii) {
            int e = tid + 256 * ii;          // < 4608
            int k = e >> 9;
            int rem = e & 511;
            int p = rem >> 5;
            int c = rem & 31;
            float sv = 0.f;
            if (p < TPX) {
                if (fastf[k][p]) {
                    short4v id4 = *(const short4v*)&widx[k][p][0];
                    float4 w4 = *reinterpret_cast<const float4*>(&wwgt[k][p][0]);
                    sv = w4.x * win[id4.x][c] + w4.y * win[id4.y][c] +
                         w4.z * win[id4.z][c] + w4.w * win[id4.w][c];
                } else {
                    int pg = xb + p;
                    float dy = offn[(size_t)(2 * k) * HW + h * W_ + pg];
                    float dx = offn[(size_t)(2 * k + 1) * HW + h * W_ + pg];
                    float ys = (float)(h + (k / 3) - 1) + dy;
                    float xs = (float)(pg + (k % 3) - 1) + dx;
                    float y0f = floorf(ys), x0f = floorf(xs);
                    int y0 = (int)y0f, x0 = (int)x0f;
                    float wy1 = ys - y0f, wy0 = 1.f - wy1;
                    float wx1 = xs - x0f, wx0 = 1.f - wx1;
                    const float* rc = rn + (size_t)(cbg + c) * HW;
#pragma unroll
                    for (int u = 0; u < 2; ++u)
#pragma unroll
                        for (int vv = 0; vv < 2; ++vv) {
                            int yy = y0 + u, xx = x0 + vv;
                            if (yy >= 0 && yy <= 55 && xx >= 0 && xx <= 55) {
                                float wgt = (u ? wy1 : wy0) * (vv ? wx1 : wx0);
                                sv += wgt * rc[yy * W_ + xx];
                            }
                        }
                }
            }
            Bs[k][p][c] = bf16_rne(sv);
        }
        __syncthreads();

        // ---- MFMA over all 9 taps, no barriers between ----
#pragma unroll
        for (int k = 0; k < KK; ++k) {
            short8 ah[4];
#pragma unroll
            for (int mt = 0; mt < 4; ++mt) {
                const ushort_t* arow = w2p +
                    (size_t)(k * 256 + (mW + mt * 16 + l15)) * 256 +
                    cbg + quad * 8;
                ah[mt] = *(const short8*)(arow);
            }
            short8 bh = ld_frag_lds(&Bs[k][l15][quad * 8]);
#pragma unroll
            for (int mt = 0; mt < 4; ++mt)
                acc[mt] = __builtin_amdgcn_mfma_f32_16x16x32_bf16(
                    ah[mt], bh, acc[mt], 0, 0, 0);
        }
    }

    // ---- epilogue: raw partial sums (bias+relu folded into next conv) ----
    const int p = l15;
    if (p < TPX) {
        float* dst = r2h + (size_t)cbh * ((size_t)N_ * CB * HW) +
                     (size_t)n * CB * HW + (size_t)h * W_ + xb + p;
#pragma unroll
        for (int mt = 0; mt < 4; ++mt)
#pragma unroll
            for (int rr = 0; rr < 4; ++rr) {
                int o = mW + mt * 16 + quad * 4 + rr;
                dst[(size_t)o * HW] = acc[mt][rr];
            }
    }
}

// ---------------------------------------------------------------------------
// kernel_launch
// ---------------------------------------------------------------------------
extern "C" void kernel_launch(void* const* d_in, const int* in_sizes, int n_in,
                              void* d_out, int out_size, void* d_ws, size_t ws_size,
                              hipStream_t stream)
{
    const float* x     = (const float*)d_in[0];
    const float* w1    = (const float*)d_in[1];
    const float* b1    = (const float*)d_in[2];
    const float* w_off = (const float*)d_in[3];
    const float* b_off = (const float*)d_in[4];
    const float* w2    = (const float*)d_in[5];
    const float* b2    = (const float*)d_in[6];
    const float* w3    = (const float*)d_in[7];
    const float* b3    = (const float*)d_in[8];
    float* out = (float*)d_out;

    float* ws  = (float*)d_ws;
    float* r    = ws;                                   // 3,211,264 f
    float* r2h  = r   + (size_t)N_ * CB * HW;           // 2 x 3,211,264 f
    float* offb = r2h + (size_t)2 * N_ * CB * HW;       //   225,792 f
    ushort_t* w1p  = (ushort_t*)(offb + (size_t)N_ * OFFC * HW); // 524,288 us
    ushort_t* w2p  = w1p + (size_t)256 * 2 * 1024;               // 589,824 us
    ushort_t* w3p  = w2p + (size_t)9 * 256 * 256;                // 524,288 us
    ushort_t* wofp = w3p + (size_t)1024 * 2 * 256;               //  73,728 us

    // 1) pack weights
    {
        int total = 256 * 1024 + 256 * 256 * 9 + 1024 * 256 + 9 * 32 * 256;
        pack_weights_kernel<<<(total + 255) / 256, 256, 0, stream>>>(
            w1, w2, w3, w_off, w1p, w2p, w3p, wofp);
    }
    // 2) r = relu(w1 . x + b1)    M=256, K=1024
    {
        dim3 grid(HW / 64, CB / 128, N_);
        conv1x1_mfma_kernel<2, true, false, false><<<grid, 256, 0, stream>>>(
            w1p, x, nullptr, nullptr, b1, nullptr, r, CB, CIN);
    }
    // 3) off = conv3x3(r, w_off) + b_off
    {
        dim3 grid(H_, N_);
        offset_mfma_kernel<<<grid, 256, 0, stream>>>(r, wofp, b_off, offb);
    }
    // 4) r2h[0] + r2h[1] = deform(r, off) . w2   (fp32 partials, K-split)
    {
        deform_mfma_kernel<<<NBLK, 256, 0, stream>>>(r, offb, w2p, r2h);
    }
    // 5) out = relu(x + w3 . relu(r2h0 + r2h1 + b2) + b3)   M=1024, K=256
    {
        dim3 grid(HW / 64, CIN / 128, N_);
        conv1x1_mfma_kernel<2, true, true, true><<<grid, 256, 0, stream>>>(
            w3p, r2h, r2h + (size_t)N_ * CB * HW, b2, b3, x, out, CIN, CB);
    }
}

// Round 2
// 411.251 us; speedup vs baseline: 1.1502x; 1.1502x over previous
//
#include <hip/hip_runtime.h>
#include <hip/hip_bf16.h>

#define N_   4
#define CIN  1024
#define H_   56
#define W_   56
#define HW   3136
#define CB   256
#define KK   9
#define OFFC 18

typedef __attribute__((ext_vector_type(8))) short short8;
typedef __attribute__((ext_vector_type(4))) short short4v;
typedef __attribute__((ext_vector_type(4))) float float4v;
typedef unsigned short ushort_t;

// fp32 -> bf16 round-to-nearest-even
__device__ inline ushort_t bf16_rne(float f) {
    unsigned int u = __float_as_uint(f);
    unsigned int r = (u + 0x7FFFu + ((u >> 16) & 1u)) >> 16;
    return (ushort_t)r;
}
__device__ inline void split_bf16(float f, ushort_t& hi, ushort_t& lo) {
    ushort_t h = bf16_rne(f);
    float hf = __uint_as_float(((unsigned int)h) << 16);
    hi = h;
    lo = bf16_rne(f - hf);
}
__device__ inline short8 ld_frag_lds(const ushort_t* base) {
    short4v a = *(const short4v*)base;
    short4v b = *(const short4v*)(base + 4);
    return __builtin_shufflevector(a, b, 0, 1, 2, 3, 4, 5, 6, 7);
}

// ---------------------------------------------------------------------------
// Pack weights.
// w1 [256][1024]      -> w1p [o][2][1024]   (hi/lo)
// w2 [256][256][9]    -> w2p [k][o][256]    (hi only)
// w3 [1024][256]      -> w3p [o][2][256]    (hi/lo)
// w_off [18][256][9]  -> wofp [k][32][256]  (hi only, m padded 18->32)
// ---------------------------------------------------------------------------
__global__ void __launch_bounds__(256) pack_weights_kernel(
    const float* __restrict__ w1, const float* __restrict__ w2,
    const float* __restrict__ w3, const float* __restrict__ w_off,
    ushort_t* __restrict__ w1p, ushort_t* __restrict__ w2p,
    ushort_t* __restrict__ w3p, ushort_t* __restrict__ wofp)
{
    int e = blockIdx.x * 256 + threadIdx.x;
    if (e < 256 * 1024) {
        int o = e >> 10, k = e & 1023;
        ushort_t hi, lo; split_bf16(w1[e], hi, lo);
        w1p[(size_t)(o * 2 + 0) * 1024 + k] = hi;
        w1p[(size_t)(o * 2 + 1) * 1024 + k] = lo;
        return;
    }
    e -= 256 * 1024;
    if (e < 256 * 256 * 9) {
        int o = e / 2304; int rem = e % 2304; int c = rem / 9; int k = rem % 9;
        w2p[(size_t)(k * 256 + o) * 256 + c] = bf16_rne(w2[e]);
        return;
    }
    e -= 256 * 256 * 9;
    if (e < 1024 * 256) {
        int o = e >> 8, k = e & 255;
        ushort_t hi, lo; split_bf16(w3[e], hi, lo);
        w3p[(size_t)(o * 2 + 0) * 256 + k] = hi;
        w3p[(size_t)(o * 2 + 1) * 256 + k] = lo;
        return;
    }
    e -= 1024 * 256;
    if (e < 9 * 32 * 256) {
        int k = e / (32 * 256);
        int rem = e % (32 * 256);
        int m = rem >> 8, c = rem & 255;
        float v = (m < OFFC) ? w_off[((size_t)m * 256 + c) * 9 + k] : 0.f;
        wofp[e] = bf16_rne(v);
    }
}

// ---------------------------------------------------------------------------
// 1x1 conv via MFMA. A = weights (hi/lo, 2 passes), B = activations (bf16).
// ---------------------------------------------------------------------------
template <int MFRAG, bool RELU, bool RESID>
__global__ void __launch_bounds__(256, 4) conv1x1_mfma_kernel(
    const ushort_t* __restrict__ Wp,   // [M][2][Kdim]
    const float* __restrict__ Xin,     // [n][Kdim][HW]
    const float* __restrict__ bias,    // [M]
    const float* __restrict__ resid,   // [n][M][HW] or null
    float* __restrict__ Cout,          // [n][M][HW]
    int M, int Kdim)
{
    __shared__ ushort_t Bs[64][36];   // [p][k], pad 36

    const int tid  = threadIdx.x;
    const int wave = tid >> 6;
    const int lane = tid & 63;
    const int l15  = lane & 15;
    const int quad = lane >> 4;
    const int pBase = blockIdx.x * 64;
    const int mBase = blockIdx.y * (MFRAG * 64) + wave * (MFRAG * 16);
    const int n     = blockIdx.z;
    const float* Xn = Xin + (size_t)n * Kdim * HW;

    float4v acc[MFRAG][4];
#pragma unroll
    for (int i = 0; i < MFRAG; ++i)
#pragma unroll
        for (int j = 0; j < 4; ++j) acc[i][j] = (float4v)(0.f);

    const int kk = tid >> 3;          // 0..31
    const int pq = (tid & 7) * 8;     // 0..56

    for (int k0 = 0; k0 < Kdim; k0 += 32) {
        const float* src = &Xn[(size_t)(k0 + kk) * HW + pBase + pq];
        float4 v0 = *reinterpret_cast<const float4*>(src);
        float4 v1 = *reinterpret_cast<const float4*>(src + 4);
        __syncthreads();   // previous iter's Bs reads are done
        float vs[8] = {v0.x, v0.y, v0.z, v0.w, v1.x, v1.y, v1.z, v1.w};
#pragma unroll
        for (int j = 0; j < 8; ++j) Bs[pq + j][kk] = bf16_rne(vs[j]);
        __syncthreads();

        short8 ah[MFRAG], al[MFRAG];
#pragma unroll
        for (int mt = 0; mt < MFRAG; ++mt) {
            const ushort_t* arow = Wp +
                ((size_t)(mBase + mt * 16 + l15) * 2) * Kdim + k0 + quad * 8;
            ah[mt] = *(const short8*)(arow);
            al[mt] = *(const short8*)(arow + Kdim);
        }
        short8 bh[4];
#pragma unroll
        for (int nt = 0; nt < 4; ++nt)
            bh[nt] = ld_frag_lds(&Bs[nt * 16 + l15][quad * 8]);
#pragma unroll
        for (int mt = 0; mt < MFRAG; ++mt)
#pragma unroll
            for (int nt = 0; nt < 4; ++nt) {
                acc[mt][nt] = __builtin_amdgcn_mfma_f32_16x16x32_bf16(
                    ah[mt], bh[nt], acc[mt][nt], 0, 0, 0);
                acc[mt][nt] = __builtin_amdgcn_mfma_f32_16x16x32_bf16(
                    al[mt], bh[nt], acc[mt][nt], 0, 0, 0);
            }
    }

#pragma unroll
    for (int mt = 0; mt < MFRAG; ++mt)
#pragma unroll
        for (int rr = 0; rr < 4; ++rr) {
            int row = mBase + mt * 16 + quad * 4 + rr;
            float bv = bias[row];
#pragma unroll
            for (int nt = 0; nt < 4; ++nt) {
                int col = pBase + nt * 16 + l15;
                size_t idx = ((size_t)n * M + row) * HW + col;
                float v = acc[mt][nt][rr] + bv;
                if (RESID) v += resid[idx];
                if (RELU)  v = fmaxf(v, 0.f);
                Cout[idx] = v;
            }
        }
}

// ---------------------------------------------------------------------------
// Offset conv 3x3 via MFMA (bf16 1-pass), LDS row-window staging.
// ---------------------------------------------------------------------------
__global__ void __launch_bounds__(256, 2) offset_mfma_kernel(
    const float* __restrict__ r,        // [n][CB][HW]
    const ushort_t* __restrict__ wofp,  // [9][32][256] bf16
    const float* __restrict__ b_off,    // [18]
    float* __restrict__ off)            // [n][18][HW]
{
    __shared__ float win[32][174];      // 3 rows x 56 cols, padded stride

    const int tid  = threadIdx.x;
    const int h    = blockIdx.x;
    const int n    = blockIdx.y;
    const int wave = tid >> 6;
    const int lane = tid & 63;
    const int l15  = lane & 15;
    const int quad = lane >> 4;
    const float* rn = r + (size_t)n * CB * HW;

    const int p = wave * 16 + l15;      // output column this lane covers

    float4v acc[2];
    acc[0] = (float4v)(0.f);
    acc[1] = (float4v)(0.f);

    for (int cb = 0; cb < CB; cb += 32) {
        __syncthreads();
        for (int f = tid; f < 32 * 3 * 14; f += 256) {
            int c = f / 42, remf = f % 42, row = remf / 14, x4 = (remf % 14) * 4;
            int yg = h - 1 + row;
            float4 v = {0.f, 0.f, 0.f, 0.f};
            if (yg >= 0 && yg < H_)
                v = *reinterpret_cast<const float4*>(
                    &rn[(size_t)(cb + c) * HW + yg * W_ + x4]);
            *reinterpret_cast<float4*>(&win[c][row * 56 + x4]) = v;
        }
        __syncthreads();

#pragma unroll
        for (int k = 0; k < KK; ++k) {
            const int ky = k / 3;
            const int dx = (k % 3) - 1;
            int x = p + dx;
            bool pvalid = (p < 56) && (x >= 0) && (x < 56);
            int xc = min(max(x, 0), 55);
            short8 bh;
#pragma unroll
            for (int j = 0; j < 8; ++j) {
                float v = win[quad * 8 + j][ky * 56 + xc];
                bh[j] = (short)bf16_rne(pvalid ? v : 0.f);
            }
#pragma unroll
            for (int mt = 0; mt < 2; ++mt) {
                const ushort_t* arow = wofp +
                    (size_t)(k * 32 + mt * 16 + l15) * 256 + cb + quad * 8;
                short8 ah = *(const short8*)arow;
                acc[mt] = __builtin_amdgcn_mfma_f32_16x16x32_bf16(
                    ah, bh, acc[mt], 0, 0, 0);
            }
        }
    }

    if (p < 56) {
#pragma unroll
        for (int mt = 0; mt < 2; ++mt)
#pragma unroll
            for (int rr = 0; rr < 4; ++rr) {
                int m = mt * 16 + quad * 4 + rr;
                if (m < OFFC)
                    off[((size_t)n * OFFC + m) * HW + h * W_ + p] =
                        acc[mt][rr] + b_off[m];
            }
    }
}

// ---------------------------------------------------------------------------
// Deformable conv via MFMA — v3: v1 structure + T14 async window prefetch +
// bijective XCD swizzle.
// 512 thr = 8 waves; each wave owns 32 output channels; N-tile 32 (28 real).
// Per cb-chunk of 32 channels: write window from PREFETCHED registers, issue
// next chunk's global loads (latency hides under build+MFMA), build all 9
// taps' B tiles, then 36 MFMAs with no intervening barriers.
// Grid: 448 1-D blocks, swizzled so each XCD owns a contiguous 28-h stripe
// of one image (30 rows x 256 ch x 56 x 4B = 1.72 MB <= 4 MB L2).
// ---------------------------------------------------------------------------
#define TPX   28
#define WROWS 5
#define WCOLS 36
#define WPOS  (WROWS * WCOLS)   // 180
#define CSTR  33
#define WITEMS (32 * WROWS * 9) // 1440 float4 stage items per chunk
#define DBLK  (H_ * 2 * N_)     // 448

__global__ void __launch_bounds__(512, 4) deform_mfma_kernel(
    const float* __restrict__ r,      // [n][CB][HW]
    const float* __restrict__ off,    // [n][18][HW]
    const ushort_t* __restrict__ w2p, // [9][256][256] bf16 hi
    const float* __restrict__ b2,
    float* __restrict__ r2)           // [n][CB][HW]
{
    __shared__ float    win[WPOS][CSTR];        // 23760 B
    __shared__ ushort_t Bs[KK][32][36];         // 20736 B
    __shared__ short    widx[KK][TPX][4];       // 2016 B
    __shared__ float    wwgt[KK][TPX][4];       // 4032 B
    __shared__ unsigned char fastf[KK][TPX];    // 252 B

    const int tid = threadIdx.x;
    const int bid = blockIdx.x;
    // bijective XCD swizzle: XCD chunk = contiguous (h, xh) range of one n
    const int swz = (bid & 7) * (DBLK >> 3) + (bid >> 3);
    const int xh  = swz & 1;
    const int h   = (swz >> 1) % H_;
    const int n   = swz / (H_ * 2);
    const int xb  = xh * TPX;
    const float* rn   = r + (size_t)n * CB * HW;
    const float* offn = off + (size_t)n * OFFC * HW;

    // ---- per-(tap, position) bilinear metadata, window-relative ----
    for (int e = tid; e < KK * TPX; e += 512) {
        int k = e / TPX, p = e % TPX;
        int pg = xb + p;
        float dy = offn[(size_t)(2 * k) * HW + h * W_ + pg];
        float dx = offn[(size_t)(2 * k + 1) * HW + h * W_ + pg];
        float ys = (float)(h + (k / 3) - 1) + dy;
        float xs = (float)(pg + (k % 3) - 1) + dx;
        float y0f = floorf(ys), x0f = floorf(xs);
        int y0 = (int)y0f, x0 = (int)x0f;
        float wy1 = ys - y0f, wy0 = 1.f - wy1;
        float wx1 = xs - x0f, wx0 = 1.f - wx1;
        bool fast = true;
#pragma unroll
        for (int u = 0; u < 2; ++u)
#pragma unroll
            for (int vv = 0; vv < 2; ++vv) {
                int yy = y0 + u, xx = x0 + vv;
                bool valid = (yy >= 0) && (yy <= 55) && (xx >= 0) && (xx <= 55);
                float wgt = valid ? (u ? wy1 : wy0) * (vv ? wx1 : wx0) : 0.f;
                int ry = yy - (h - 2);
                int rx = xx - (xb - 4);
                if (wgt != 0.f &&
                    (ry < 0 || ry >= WROWS || rx < 0 || rx >= WCOLS))
                    fast = false;
                int ryc = min(max(ry, 0), WROWS - 1);
                int rxc = min(max(rx, 0), WCOLS - 1);
                widx[k][p][u * 2 + vv] = (short)(ryc * WCOLS + rxc);
                wwgt[k][p][u * 2 + vv] = wgt;
            }
        fastf[k][p] = fast ? 1 : 0;
    }

    const int wave = tid >> 6;     // 0..7
    const int lane = tid & 63;
    const int l15  = lane & 15;
    const int quad = lane >> 4;
    const int mW   = wave * 32;

    float4v acc[2][2];
#pragma unroll
    for (int i = 0; i < 2; ++i)
#pragma unroll
        for (int j = 0; j < 2; ++j) acc[i][j] = (float4v)(0.f);

    // ---- T14 prefetch: window loads for chunk cbg into registers ----
    float4 pre[3];
    auto wload = [&](int f, int cbg) -> float4 {
        int c = f / 45, remf = f % 45, row = remf / 9, q = remf % 9;
        int yg = min(max(h - 2 + row, 0), H_ - 1);
        int xg = xb - 4 + q * 4;
        const float* src = &rn[(size_t)(cbg + c) * HW + yg * W_];
        float4 v;
        if (xg >= 0 && xg <= W_ - 4) {
            v = *reinterpret_cast<const float4*>(src + xg);
        } else {
            v.x = src[min(max(xg + 0, 0), W_ - 1)];
            v.y = src[min(max(xg + 1, 0), W_ - 1)];
            v.z = src[min(max(xg + 2, 0), W_ - 1)];
            v.w = src[min(max(xg + 3, 0), W_ - 1)];
        }
        return v;
    };

#pragma unroll
    for (int i = 0; i < 3; ++i) {
        int f = tid + 512 * i;
        if (f < WITEMS) pre[i] = wload(f, 0);
    }

    for (int cb = 0; cb < CB; cb += 32) {
        __syncthreads();  // prev build (win readers) + prev MFMA (Bs readers)
        // ---- write window from prefetched regs ----
#pragma unroll
        for (int i = 0; i < 3; ++i) {
            int f = tid + 512 * i;
            if (f < WITEMS) {
                int c = f / 45, remf = f % 45, row = remf / 9, q = remf % 9;
                int pos = row * WCOLS + q * 4;
                float4 v = pre[i];
                win[pos + 0][c] = v.x;
                win[pos + 1][c] = v.y;
                win[pos + 2][c] = v.z;
                win[pos + 3][c] = v.w;
            }
        }
        // ---- issue next chunk's loads; latency hides under build+MFMA ----
        if (cb + 32 < CB) {
#pragma unroll
            for (int i = 0; i < 3; ++i) {
                int f = tid + 512 * i;
                if (f < WITEMS) pre[i] = wload(f, cb + 32);
            }
        }
        __syncthreads();

        // ---- build B tiles for ALL 9 taps: 9 x 32 p x 32 ch = 9216 ----
#pragma unroll
        for (int ii = 0; ii < 18; ++ii) {
            int e = tid + 512 * ii;          // < 9216
            int k = e >> 10;
            int rem = e & 1023;
            int p = rem >> 5;
            int c = rem & 31;
            float sv = 0.f;
            if (p < TPX) {
                if (fastf[k][p]) {
                    short4v id4 = *(const short4v*)&widx[k][p][0];
                    float4 w4 = *reinterpret_cast<const float4*>(&wwgt[k][p][0]);
                    sv = w4.x * win[id4.x][c] + w4.y * win[id4.y][c] +
                         w4.z * win[id4.z][c] + w4.w * win[id4.w][c];
                } else {
                    int pg = xb + p;
                    float dy = offn[(size_t)(2 * k) * HW + h * W_ + pg];
                    float dx = offn[(size_t)(2 * k + 1) * HW + h * W_ + pg];
                    float ys = (float)(h + (k / 3) - 1) + dy;
                    float xs = (float)(pg + (k % 3) - 1) + dx;
                    float y0f = floorf(ys), x0f = floorf(xs);
                    int y0 = (int)y0f, x0 = (int)x0f;
                    float wy1 = ys - y0f, wy0 = 1.f - wy1;
                    float wx1 = xs - x0f, wx0 = 1.f - wx1;
                    const float* rc = rn + (size_t)(cb + c) * HW;
#pragma unroll
                    for (int u = 0; u < 2; ++u)
#pragma unroll
                        for (int vv = 0; vv < 2; ++vv) {
                            int yy = y0 + u, xx = x0 + vv;
                            if (yy >= 0 && yy <= 55 && xx >= 0 && xx <= 55) {
                                float wgt = (u ? wy1 : wy0) * (vv ? wx1 : wx0);
                                sv += wgt * rc[yy * W_ + xx];
                            }
                        }
                }
            }
            Bs[k][p][c] = bf16_rne(sv);
        }
        __syncthreads();

        // ---- MFMA over all 9 taps, no barriers between ----
#pragma unroll
        for (int k = 0; k < KK; ++k) {
            short8 ah[2];
#pragma unroll
            for (int mt = 0; mt < 2; ++mt) {
                const ushort_t* arow = w2p +
                    (size_t)(k * 256 + (mW + mt * 16 + l15)) * 256 +
                    cb + quad * 8;
                ah[mt] = *(const short8*)(arow);
            }
            short8 bh[2];
#pragma unroll
            for (int nt = 0; nt < 2; ++nt)
                bh[nt] = ld_frag_lds(&Bs[k][nt * 16 + l15][quad * 8]);
#pragma unroll
            for (int mt = 0; mt < 2; ++mt)
#pragma unroll
                for (int nt = 0; nt < 2; ++nt)
                    acc[mt][nt] = __builtin_amdgcn_mfma_f32_16x16x32_bf16(
                        ah[mt], bh[nt], acc[mt][nt], 0, 0, 0);
        }
    }

    // ---- epilogue: bias + relu ----
#pragma unroll
    for (int mt = 0; mt < 2; ++mt)
#pragma unroll
        for (int rr = 0; rr < 4; ++rr) {
            int o = mW + mt * 16 + quad * 4 + rr;
            float bv = b2[o];
#pragma unroll
            for (int nt = 0; nt < 2; ++nt) {
                int p = nt * 16 + l15;
                if (p < TPX) {
                    float v = fmaxf(acc[mt][nt][rr] + bv, 0.f);
                    r2[((size_t)n * CB + o) * HW + h * W_ + xb + p] = v;
                }
            }
        }
}

// ---------------------------------------------------------------------------
// kernel_launch
// ---------------------------------------------------------------------------
extern "C" void kernel_launch(void* const* d_in, const int* in_sizes, int n_in,
                              void* d_out, int out_size, void* d_ws, size_t ws_size,
                              hipStream_t stream)
{
    const float* x     = (const float*)d_in[0];
    const float* w1    = (const float*)d_in[1];
    const float* b1    = (const float*)d_in[2];
    const float* w_off = (const float*)d_in[3];
    const float* b_off = (const float*)d_in[4];
    const float* w2    = (const float*)d_in[5];
    const float* b2    = (const float*)d_in[6];
    const float* w3    = (const float*)d_in[7];
    const float* b3    = (const float*)d_in[8];
    float* out = (float*)d_out;

    float* ws  = (float*)d_ws;
    float* r    = ws;                             // 3,211,264 f
    float* r2   = r  + (size_t)N_ * CB * HW;      // 3,211,264 f
    float* offb = r2 + (size_t)N_ * CB * HW;      //   225,792 f
    ushort_t* w1p  = (ushort_t*)(offb + (size_t)N_ * OFFC * HW); // 524,288 us
    ushort_t* w2p  = w1p + (size_t)256 * 2 * 1024;               //   589,824 us
    ushort_t* w3p  = w2p + (size_t)9 * 256 * 256;                //   524,288 us
    ushort_t* wofp = w3p + (size_t)1024 * 2 * 256;               //    73,728 us

    // 1) pack weights
    {
        int total = 256 * 1024 + 256 * 256 * 9 + 1024 * 256 + 9 * 32 * 256;
        pack_weights_kernel<<<(total + 255) / 256, 256, 0, stream>>>(
            w1, w2, w3, w_off, w1p, w2p, w3p, wofp);
    }
    // 2) r = relu(w1 . x + b1)    M=256, K=1024
    {
        dim3 grid(HW / 64, CB / 128, N_);
        conv1x1_mfma_kernel<2, true, false><<<grid, 256, 0, stream>>>(
            w1p, x, b1, nullptr, r, CB, CIN);
    }
    // 3) off = conv3x3(r, w_off) + b_off
    {
        dim3 grid(H_, N_);
        offset_mfma_kernel<<<grid, 256, 0, stream>>>(r, wofp, b_off, offb);
    }
    // 4) r2 = relu(deform(r, off) . w2 + b2)
    {
        deform_mfma_kernel<<<DBLK, 512, 0, stream>>>(r, offb, w2p, b2, r2);
    }
    // 5) out = relu(x + w3 . r2 + b3)   M=1024, K=256
    {
        dim3 grid(HW / 64, CIN / 128, N_);
        conv1x1_mfma_kernel<2, true, true><<<grid, 256, 0, stream>>>(
            w3p, r2, b3, x, out, CIN, CB);
    }
}

// Round 3
// 363.450 us; speedup vs baseline: 1.3015x; 1.1315x over previous
//
#include <hip/hip_runtime.h>
#include <hip/hip_bf16.h>

#define N_   4
#define CIN  1024
#define H_   56
#define W_   56
#define HW   3136
#define CB   256
#define KK   9
#define OFFC 18

typedef __attribute__((ext_vector_type(8))) short short8;
typedef __attribute__((ext_vector_type(4))) short short4v;
typedef __attribute__((ext_vector_type(4))) float float4v;
typedef unsigned short ushort_t;

// fp32 -> bf16 round-to-nearest-even
__device__ inline ushort_t bf16_rne(float f) {
    unsigned int u = __float_as_uint(f);
    unsigned int r = (u + 0x7FFFu + ((u >> 16) & 1u)) >> 16;
    return (ushort_t)r;
}
__device__ inline void split_bf16(float f, ushort_t& hi, ushort_t& lo) {
    ushort_t h = bf16_rne(f);
    float hf = __uint_as_float(((unsigned int)h) << 16);
    hi = h;
    lo = bf16_rne(f - hf);
}
__device__ inline short8 ld_frag_lds(const ushort_t* base) {
    short4v a = *(const short4v*)base;
    short4v b = *(const short4v*)(base + 4);
    return __builtin_shufflevector(a, b, 0, 1, 2, 3, 4, 5, 6, 7);
}
// Barrier that does NOT drain vmcnt (keeps prefetch global loads in flight).
// LDS producer->consumer only needs lgkmcnt(0) before s_barrier (m201 idiom).
__device__ inline void lds_barrier() {
    asm volatile("s_waitcnt lgkmcnt(0)" ::: "memory");
    __builtin_amdgcn_s_barrier();
    __builtin_amdgcn_sched_barrier(0);
}

// ---------------------------------------------------------------------------
// Pack weights.
// w1 [256][1024]      -> w1p [o][2][1024]   (hi/lo)
// w2 [256][256][9]    -> w2p [k][o][256]    (hi only)
// w3 [1024][256]      -> w3p [o][2][256]    (hi/lo)
// w_off [18][256][9]  -> wofp [k][32][256]  (hi only, m padded 18->32)
// ---------------------------------------------------------------------------
__global__ void __launch_bounds__(256) pack_weights_kernel(
    const float* __restrict__ w1, const float* __restrict__ w2,
    const float* __restrict__ w3, const float* __restrict__ w_off,
    ushort_t* __restrict__ w1p, ushort_t* __restrict__ w2p,
    ushort_t* __restrict__ w3p, ushort_t* __restrict__ wofp)
{
    int e = blockIdx.x * 256 + threadIdx.x;
    if (e < 256 * 1024) {
        int o = e >> 10, k = e & 1023;
        ushort_t hi, lo; split_bf16(w1[e], hi, lo);
        w1p[(size_t)(o * 2 + 0) * 1024 + k] = hi;
        w1p[(size_t)(o * 2 + 1) * 1024 + k] = lo;
        return;
    }
    e -= 256 * 1024;
    if (e < 256 * 256 * 9) {
        int o = e / 2304; int rem = e % 2304; int c = rem / 9; int k = rem % 9;
        w2p[(size_t)(k * 256 + o) * 256 + c] = bf16_rne(w2[e]);
        return;
    }
    e -= 256 * 256 * 9;
    if (e < 1024 * 256) {
        int o = e >> 8, k = e & 255;
        ushort_t hi, lo; split_bf16(w3[e], hi, lo);
        w3p[(size_t)(o * 2 + 0) * 256 + k] = hi;
        w3p[(size_t)(o * 2 + 1) * 256 + k] = lo;
        return;
    }
    e -= 1024 * 256;
    if (e < 9 * 32 * 256) {
        int k = e / (32 * 256);
        int rem = e % (32 * 256);
        int m = rem >> 8, c = rem & 255;
        float v = (m < OFFC) ? w_off[((size_t)m * 256 + c) * 9 + k] : 0.f;
        wofp[e] = bf16_rne(v);
    }
}

// ---------------------------------------------------------------------------
// 1x1 conv via MFMA. A = weights (hi/lo, 2 passes), B = activations (bf16).
// ---------------------------------------------------------------------------
template <int MFRAG, bool RELU, bool RESID>
__global__ void __launch_bounds__(256, 4) conv1x1_mfma_kernel(
    const ushort_t* __restrict__ Wp,   // [M][2][Kdim]
    const float* __restrict__ Xin,     // [n][Kdim][HW]
    const float* __restrict__ bias,    // [M]
    const float* __restrict__ resid,   // [n][M][HW] or null
    float* __restrict__ Cout,          // [n][M][HW]
    int M, int Kdim)
{
    __shared__ ushort_t Bs[64][36];   // [p][k], pad 36

    const int tid  = threadIdx.x;
    const int wave = tid >> 6;
    const int lane = tid & 63;
    const int l15  = lane & 15;
    const int quad = lane >> 4;
    const int pBase = blockIdx.x * 64;
    const int mBase = blockIdx.y * (MFRAG * 64) + wave * (MFRAG * 16);
    const int n     = blockIdx.z;
    const float* Xn = Xin + (size_t)n * Kdim * HW;

    float4v acc[MFRAG][4];
#pragma unroll
    for (int i = 0; i < MFRAG; ++i)
#pragma unroll
        for (int j = 0; j < 4; ++j) acc[i][j] = (float4v)(0.f);

    const int kk = tid >> 3;          // 0..31
    const int pq = (tid & 7) * 8;     // 0..56

    for (int k0 = 0; k0 < Kdim; k0 += 32) {
        const float* src = &Xn[(size_t)(k0 + kk) * HW + pBase + pq];
        float4 v0 = *reinterpret_cast<const float4*>(src);
        float4 v1 = *reinterpret_cast<const float4*>(src + 4);
        __syncthreads();   // previous iter's Bs reads are done
        float vs[8] = {v0.x, v0.y, v0.z, v0.w, v1.x, v1.y, v1.z, v1.w};
#pragma unroll
        for (int j = 0; j < 8; ++j) Bs[pq + j][kk] = bf16_rne(vs[j]);
        __syncthreads();

        short8 ah[MFRAG], al[MFRAG];
#pragma unroll
        for (int mt = 0; mt < MFRAG; ++mt) {
            const ushort_t* arow = Wp +
                ((size_t)(mBase + mt * 16 + l15) * 2) * Kdim + k0 + quad * 8;
            ah[mt] = *(const short8*)(arow);
            al[mt] = *(const short8*)(arow + Kdim);
        }
        short8 bh[4];
#pragma unroll
        for (int nt = 0; nt < 4; ++nt)
            bh[nt] = ld_frag_lds(&Bs[nt * 16 + l15][quad * 8]);
#pragma unroll
        for (int mt = 0; mt < MFRAG; ++mt)
#pragma unroll
            for (int nt = 0; nt < 4; ++nt) {
                acc[mt][nt] = __builtin_amdgcn_mfma_f32_16x16x32_bf16(
                    ah[mt], bh[nt], acc[mt][nt], 0, 0, 0);
                acc[mt][nt] = __builtin_amdgcn_mfma_f32_16x16x32_bf16(
                    al[mt], bh[nt], acc[mt][nt], 0, 0, 0);
            }
    }

#pragma unroll
    for (int mt = 0; mt < MFRAG; ++mt)
#pragma unroll
        for (int rr = 0; rr < 4; ++rr) {
            int row = mBase + mt * 16 + quad * 4 + rr;
            float bv = bias[row];
#pragma unroll
            for (int nt = 0; nt < 4; ++nt) {
                int col = pBase + nt * 16 + l15;
                size_t idx = ((size_t)n * M + row) * HW + col;
                float v = acc[mt][nt][rr] + bv;
                if (RESID) v += resid[idx];
                if (RELU)  v = fmaxf(v, 0.f);
                Cout[idx] = v;
            }
        }
}

// ---------------------------------------------------------------------------
// Offset conv 3x3 via MFMA (bf16 1-pass), LDS row-window staging.
// ---------------------------------------------------------------------------
__global__ void __launch_bounds__(256, 2) offset_mfma_kernel(
    const float* __restrict__ r,        // [n][CB][HW]
    const ushort_t* __restrict__ wofp,  // [9][32][256] bf16
    const float* __restrict__ b_off,    // [18]
    float* __restrict__ off)            // [n][18][HW]
{
    __shared__ float win[32][174];      // 3 rows x 56 cols, padded stride

    const int tid  = threadIdx.x;
    const int h    = blockIdx.x;
    const int n    = blockIdx.y;
    const int wave = tid >> 6;
    const int lane = tid & 63;
    const int l15  = lane & 15;
    const int quad = lane >> 4;
    const float* rn = r + (size_t)n * CB * HW;

    const int p = wave * 16 + l15;      // output column this lane covers

    float4v acc[2];
    acc[0] = (float4v)(0.f);
    acc[1] = (float4v)(0.f);

    for (int cb = 0; cb < CB; cb += 32) {
        __syncthreads();
        for (int f = tid; f < 32 * 3 * 14; f += 256) {
            int c = f / 42, remf = f % 42, row = remf / 14, x4 = (remf % 14) * 4;
            int yg = h - 1 + row;
            float4 v = {0.f, 0.f, 0.f, 0.f};
            if (yg >= 0 && yg < H_)
                v = *reinterpret_cast<const float4*>(
                    &rn[(size_t)(cb + c) * HW + yg * W_ + x4]);
            *reinterpret_cast<float4*>(&win[c][row * 56 + x4]) = v;
        }
        __syncthreads();

#pragma unroll
        for (int k = 0; k < KK; ++k) {
            const int ky = k / 3;
            const int dx = (k % 3) - 1;
            int x = p + dx;
            bool pvalid = (p < 56) && (x >= 0) && (x < 56);
            int xc = min(max(x, 0), 55);
            short8 bh;
#pragma unroll
            for (int j = 0; j < 8; ++j) {
                float v = win[quad * 8 + j][ky * 56 + xc];
                bh[j] = (short)bf16_rne(pvalid ? v : 0.f);
            }
#pragma unroll
            for (int mt = 0; mt < 2; ++mt) {
                const ushort_t* arow = wofp +
                    (size_t)(k * 32 + mt * 16 + l15) * 256 + cb + quad * 8;
                short8 ah = *(const short8*)arow;
                acc[mt] = __builtin_amdgcn_mfma_f32_16x16x32_bf16(
                    ah, bh, acc[mt], 0, 0, 0);
            }
        }
    }

    if (p < 56) {
#pragma unroll
        for (int mt = 0; mt < 2; ++mt)
#pragma unroll
            for (int rr = 0; rr < 4; ++rr) {
                int m = mt * 16 + quad * 4 + rr;
                if (m < OFFC)
                    off[((size_t)n * OFFC + m) * HW + h * W_ + p] =
                        acc[mt][rr] + b_off[m];
            }
    }
}

// ---------------------------------------------------------------------------
// Deformable conv via MFMA — v4: register metadata + pair-owned build +
// lgkmcnt-only barriers (2 per chunk) + true async window prefetch.
// 512 thr = 8 waves; each wave owns 32 output channels; N-tile 32 (28 real).
// Build: thread tid<288 owns (k,p) = (tid/32, tid%32); bilinear metadata
// lives in REGISTERS (computed once); per chunk it gathers 32 channels as
// 8 x (16 ds_read_b32 + 16 FMA + 1 ds_write_b64). Pad p>=28 = zero weights.
// Chunk loop: [win-write from pre | prefetch next | barA | build | barB |
// MFMA+setprio]. Barriers wait lgkmcnt only -> prefetch vmcnt stays in
// flight across the whole chunk (T14).
// ---------------------------------------------------------------------------
#define TPX   28
#define WROWS 5
#define WCOLS 36
#define WPOS  (WROWS * WCOLS)   // 180
#define CSTR  33
#define WITEMS (32 * WROWS * 9) // 1440 float4 stage items per chunk
#define DBLK  (H_ * 2 * N_)     // 448

__global__ void __launch_bounds__(512, 2) deform_mfma_kernel(
    const float* __restrict__ r,      // [n][CB][HW]
    const float* __restrict__ off,    // [n][18][HW]
    const ushort_t* __restrict__ w2p, // [9][256][256] bf16 hi
    const float* __restrict__ b2,
    float* __restrict__ r2)           // [n][CB][HW]
{
    __shared__ float    win[WPOS][CSTR];        // 23760 B
    __shared__ ushort_t Bs[KK][32][36];         // 20736 B

    const int tid = threadIdx.x;
    const int bid = blockIdx.x;
    // bijective XCD swizzle: XCD chunk = contiguous (h, xh) range of one n
    const int swz = (bid & 7) * (DBLK >> 3) + (bid >> 3);
    const int xh  = swz & 1;
    const int h   = (swz >> 1) % H_;
    const int n   = swz / (H_ * 2);
    const int xb  = xh * TPX;
    const float* rn   = r + (size_t)n * CB * HW;
    const float* offn = off + (size_t)n * OFFC * HW;

    // ---- per-thread build metadata in registers (tid < 288 owns (k,p)) ----
    int   bi0 = 0, bi1 = 0, bi2 = 0, bi3 = 0;          // win row indices
    float bw0 = 0.f, bw1 = 0.f, bw2 = 0.f, bw3 = 0.f;  // bilinear weights
    int   go0 = 0, go1 = 0, go2 = 0, go3 = 0;          // global offsets (slow)
    bool  bfast = true;
    const bool bactive = (tid < 288);
    const int  bk = bactive ? (tid / 32) : 0;
    const int  bp = bactive ? (tid % 32) : 0;
    if (bactive && bp < TPX) {
        int pg = xb + bp;
        float dy = offn[(size_t)(2 * bk) * HW + h * W_ + pg];
        float dx = offn[(size_t)(2 * bk + 1) * HW + h * W_ + pg];
        float ys = (float)(h + (bk / 3) - 1) + dy;
        float xs = (float)(pg + (bk % 3) - 1) + dx;
        float y0f = floorf(ys), x0f = floorf(xs);
        int y0 = (int)y0f, x0 = (int)x0f;
        float wy1 = ys - y0f, wy0 = 1.f - wy1;
        float wx1 = xs - x0f, wx0 = 1.f - wx1;
        int   wid[4]; float wg[4]; int gof[4]; bool fast = true;
#pragma unroll
        for (int u = 0; u < 2; ++u)
#pragma unroll
            for (int vv = 0; vv < 2; ++vv) {
                int yy = y0 + u, xx = x0 + vv;
                bool valid = (yy >= 0) && (yy <= 55) && (xx >= 0) && (xx <= 55);
                float wgt = valid ? (u ? wy1 : wy0) * (vv ? wx1 : wx0) : 0.f;
                int ry = yy - (h - 2);
                int rx = xx - (xb - 4);
                if (wgt != 0.f &&
                    (ry < 0 || ry >= WROWS || rx < 0 || rx >= WCOLS))
                    fast = false;
                int idx = min(max(ry, 0), WROWS - 1) * WCOLS +
                          min(max(rx, 0), WCOLS - 1);
                wid[u * 2 + vv] = idx;
                wg[u * 2 + vv]  = wgt;
                gof[u * 2 + vv] = valid ? (yy * W_ + xx) : 0;
            }
        bfast = fast;
        bi0 = wid[0]; bi1 = wid[1]; bi2 = wid[2]; bi3 = wid[3];
        bw0 = wg[0];  bw1 = wg[1];  bw2 = wg[2];  bw3 = wg[3];
        go0 = gof[0]; go1 = gof[1]; go2 = gof[2]; go3 = gof[3];
    }
    // bactive && bp>=TPX: all weights 0, fast path -> writes zeros (pad rows)

    const int wave = tid >> 6;     // 0..7
    const int lane = tid & 63;
    const int l15  = lane & 15;
    const int quad = lane >> 4;
    const int mW   = wave * 32;

    float4v acc[2][2];
#pragma unroll
    for (int i = 0; i < 2; ++i)
#pragma unroll
        for (int j = 0; j < 2; ++j) acc[i][j] = (float4v)(0.f);

    // ---- window stage loader (global -> regs) ----
    auto wload = [&](int f, int cbg) -> float4 {
        int c = f / 45, remf = f % 45, row = remf / 9, q = remf % 9;
        int yg = min(max(h - 2 + row, 0), H_ - 1);
        int xg = xb - 4 + q * 4;
        const float* src = &rn[(size_t)(cbg + c) * HW + yg * W_];
        float4 v;
        if (xg >= 0 && xg <= W_ - 4) {
            v = *reinterpret_cast<const float4*>(src + xg);
        } else {
            v.x = src[min(max(xg + 0, 0), W_ - 1)];
            v.y = src[min(max(xg + 1, 0), W_ - 1)];
            v.z = src[min(max(xg + 2, 0), W_ - 1)];
            v.w = src[min(max(xg + 3, 0), W_ - 1)];
        }
        return v;
    };

    float4 pre[3];
#pragma unroll
    for (int i = 0; i < 3; ++i) {
        int f = tid + 512 * i;
        if (f < WITEMS) pre[i] = wload(f, 0);
    }

    for (int cb = 0; cb < CB; cb += 32) {
        // ---- write window from prefetched regs (prev build done @ barB) ----
#pragma unroll
        for (int i = 0; i < 3; ++i) {
            int f = tid + 512 * i;
            if (f < WITEMS) {
                int c = f / 45, remf = f % 45, row = remf / 9, q = remf % 9;
                int pos = row * WCOLS + q * 4;
                float4 v = pre[i];
                win[pos + 0][c] = v.x;
                win[pos + 1][c] = v.y;
                win[pos + 2][c] = v.z;
                win[pos + 3][c] = v.w;
            }
        }
        // ---- issue next chunk's loads; stay in flight across barriers ----
        if (cb + 32 < CB) {
#pragma unroll
            for (int i = 0; i < 3; ++i) {
                int f = tid + 512 * i;
                if (f < WITEMS) pre[i] = wload(f, cb + 32);
            }
        }
        lds_barrier();   // barA: win visible; prev MFMA done with Bs

        // ---- build: owner thread gathers its (k,p) across 32 channels ----
        if (bactive) {
#pragma unroll
            for (int c4 = 0; c4 < 32; c4 += 4) {
                float s[4];
                if (bfast) {
#pragma unroll
                    for (int j = 0; j < 4; ++j) {
                        int c = c4 + j;
                        s[j] = bw0 * win[bi0][c] + bw1 * win[bi1][c] +
                               bw2 * win[bi2][c] + bw3 * win[bi3][c];
                    }
                } else {
#pragma unroll
                    for (int j = 0; j < 4; ++j) {
                        const float* rc = rn + (size_t)(cb + c4 + j) * HW;
                        s[j] = bw0 * rc[go0] + bw1 * rc[go1] +
                               bw2 * rc[go2] + bw3 * rc[go3];
                    }
                }
                short4v pk;
#pragma unroll
                for (int j = 0; j < 4; ++j) pk[j] = (short)bf16_rne(s[j]);
                *(short4v*)&Bs[bk][bp][c4] = pk;
            }
        }
        lds_barrier();   // barB: Bs visible

        // ---- MFMA over all 9 taps, no barriers between ----
        __builtin_amdgcn_s_setprio(1);
#pragma unroll
        for (int k = 0; k < KK; ++k) {
            short8 ah[2];
#pragma unroll
            for (int mt = 0; mt < 2; ++mt) {
                const ushort_t* arow = w2p +
                    (size_t)(k * 256 + (mW + mt * 16 + l15)) * 256 +
                    cb + quad * 8;
                ah[mt] = *(const short8*)(arow);
            }
            short8 bh[2];
#pragma unroll
            for (int nt = 0; nt < 2; ++nt)
                bh[nt] = ld_frag_lds(&Bs[k][nt * 16 + l15][quad * 8]);
#pragma unroll
            for (int mt = 0; mt < 2; ++mt)
#pragma unroll
                for (int nt = 0; nt < 2; ++nt)
                    acc[mt][nt] = __builtin_amdgcn_mfma_f32_16x16x32_bf16(
                        ah[mt], bh[nt], acc[mt][nt], 0, 0, 0);
        }
        __builtin_amdgcn_s_setprio(0);
    }

    // ---- epilogue: bias + relu ----
#pragma unroll
    for (int mt = 0; mt < 2; ++mt)
#pragma unroll
        for (int rr = 0; rr < 4; ++rr) {
            int o = mW + mt * 16 + quad * 4 + rr;
            float bv = b2[o];
#pragma unroll
            for (int nt = 0; nt < 2; ++nt) {
                int p = nt * 16 + l15;
                if (p < TPX) {
                    float v = fmaxf(acc[mt][nt][rr] + bv, 0.f);
                    r2[((size_t)n * CB + o) * HW + h * W_ + xb + p] = v;
                }
            }
        }
}

// ---------------------------------------------------------------------------
// kernel_launch
// ---------------------------------------------------------------------------
extern "C" void kernel_launch(void* const* d_in, const int* in_sizes, int n_in,
                              void* d_out, int out_size, void* d_ws, size_t ws_size,
                              hipStream_t stream)
{
    const float* x     = (const float*)d_in[0];
    const float* w1    = (const float*)d_in[1];
    const float* b1    = (const float*)d_in[2];
    const float* w_off = (const float*)d_in[3];
    const float* b_off = (const float*)d_in[4];
    const float* w2    = (const float*)d_in[5];
    const float* b2    = (const float*)d_in[6];
    const float* w3    = (const float*)d_in[7];
    const float* b3    = (const float*)d_in[8];
    float* out = (float*)d_out;

    float* ws  = (float*)d_ws;
    float* r    = ws;                             // 3,211,264 f
    float* r2   = r  + (size_t)N_ * CB * HW;      // 3,211,264 f
    float* offb = r2 + (size_t)N_ * CB * HW;      //   225,792 f
    ushort_t* w1p  = (ushort_t*)(offb + (size_t)N_ * OFFC * HW); // 524,288 us
    ushort_t* w2p  = w1p + (size_t)256 * 2 * 1024;               //   589,824 us
    ushort_t* w3p  = w2p + (size_t)9 * 256 * 256;                //   524,288 us
    ushort_t* wofp = w3p + (size_t)1024 * 2 * 256;               //    73,728 us

    // 1) pack weights
    {
        int total = 256 * 1024 + 256 * 256 * 9 + 1024 * 256 + 9 * 32 * 256;
        pack_weights_kernel<<<(total + 255) / 256, 256, 0, stream>>>(
            w1, w2, w3, w_off, w1p, w2p, w3p, wofp);
    }
    // 2) r = relu(w1 . x + b1)    M=256, K=1024
    {
        dim3 grid(HW / 64, CB / 128, N_);
        conv1x1_mfma_kernel<2, true, false><<<grid, 256, 0, stream>>>(
            w1p, x, b1, nullptr, r, CB, CIN);
    }
    // 3) off = conv3x3(r, w_off) + b_off
    {
        dim3 grid(H_, N_);
        offset_mfma_kernel<<<grid, 256, 0, stream>>>(r, wofp, b_off, offb);
    }
    // 4) r2 = relu(deform(r, off) . w2 + b2)
    {
        deform_mfma_kernel<<<DBLK, 512, 0, stream>>>(r, offb, w2p, b2, r2);
    }
    // 5) out = relu(x + w3 . r2 + b3)   M=1024, K=256
    {
        dim3 grid(HW / 64, CIN / 128, N_);
        conv1x1_mfma_kernel<2, true, true><<<grid, 256, 0, stream>>>(
            w3p, r2, b3, x, out, CIN, CB);
    }
}